// Round 14
// baseline (577.511 us; speedup 1.0000x reference)
//
#include <hip/hip_runtime.h>
#include <hip/hip_bf16.h>

#define E_EDGES   250000
#define D_NODE    128
#define D_EMB     200
#define D_STATIC  64
#define F_DIM     520
#define NT        33        // n-tiles of 16 (528 real cols; tile 32 = cols 512..527)
#define KT        17        // k-steps of 32 (544 k padded; cols 528..543 zero)
#define RS        552       // LDS row stride bf16. MUST stay 16B-aligned (R9/R10:
                            // RS=564 = 8 mod 16 made odd-row ds_read_b128 misaligned
                            // -> 2x LDS time, -90%). 552 = 1104B, 276 dw mod 32 = 20,
                            // gcd 4 -> uniform 2 lanes/bank = free (m136). Optimal.
#define BM        64        // edges (rows) per block
#define SMEM_BYTES (BM * RS * 2)   // 70656 B -> 2 independent blocks/CU
                            // (R11/R13 lesson: 1 big block = barrier lockstep stall;
                            //  2 blocks decouple gather/epilogue from K-loop)

typedef __attribute__((ext_vector_type(8))) short frag_t;   // 8 bf16 = 4 VGPR
typedef __attribute__((ext_vector_type(4))) float f32x4;

// Bit-twiddle RNE conversions (branchless VALU; exonerated by R10 factorial).
__device__ __forceinline__ unsigned short f2bf(float x) {
    union { float f; unsigned int u; } v; v.f = x;
    unsigned int r = v.u + 0x7FFFu + ((v.u >> 16) & 1u);   // RTNE
    return (unsigned short)(r >> 16);
}
__device__ __forceinline__ float bf2f(unsigned short u) {
    union { float f; unsigned int i; } v; v.i = ((unsigned int)u) << 16; return v.f;
}
__device__ __forceinline__ float elu(float z) {
    return (z > 0.0f) ? z : (__expf(z) - 1.0f);
}

// Pack W[k][n] (f32, row-major, ldw) into fragment-ordered bf16:
// Wp[((nt*KT + kt)*64 + lane)*8 + j] = W[kt*32 + (lane>>4)*8 + j][nt*16 + (lane&15)]
// zero outside (krows, ncols).
__global__ void pack_w_kernel(const float* __restrict__ W, unsigned short* __restrict__ Wp,
                              int ntiles, int krows, int ncols, int ldw) {
    int t = blockIdx.x * blockDim.x + threadIdx.x;
    if (t >= ntiles * KT * 64) return;
    int nt   = t / (KT * 64);
    int rem  = t % (KT * 64);
    int kt   = rem / 64;
    int lane = rem % 64;
    int n  = nt * 16 + (lane & 15);
    int kb = kt * 32 + (lane >> 4) * 8;
    unsigned short v[8];
    #pragma unroll
    for (int j = 0; j < 8; ++j) {
        int k = kb + j;
        float w = (k < krows && n < ncols) ? W[(long long)k * ldw + n] : 0.0f;
        v[j] = f2bf(w);
    }
    unsigned short* dst = Wp + (long long)t * 8;
    #pragma unroll
    for (int j = 0; j < 8; ++j) dst[j] = v[j];
}

// One residual-MLP layer, in place on the 64x552 bf16 LDS panel.
// 8 waves: wave w owns ntiles 4w..4w+3 over all 64 rows (acc[4][4]=64 regs);
// waves 0..3 also fold tile 32 (cols 512..527), rows 16w..16w+15.
// R14 change vs R12 (single-variable): restore depth-1 B PING-PONG.
// R12's single-buffered B serialized each kt: MFMA-burst -> WAR-stalled B-load
// -> ~200cy L2 wait. Ping-pong (+16 arch regs) overlaps next-kt loads with
// current-kt MFMAs. K-loop stays ROLLED (R4-R6: unrolled bodies spill ~500MB).
__device__ __forceinline__ void layer_pass(char* __restrict__ h,
                                           const unsigned short* __restrict__ Wp,
                                           const float* __restrict__ bias,
                                           int wave, int lane) {
    const int idx = lane & 15;
    const int grp = lane >> 4;
    const int nt0 = wave * 4;
    const bool t32 = (wave < 4);
    const char* wb = (const char*)Wp + (size_t)lane * 16;
    const char* abase   = h + (size_t)idx * (RS * 2) + grp * 16;
    const char* a32base = h + (size_t)(wave * 16 + idx) * (RS * 2) + grp * 16;

    f32x4 acc[4][4];
    #pragma unroll
    for (int t = 0; t < 4; ++t)
        #pragma unroll
        for (int m = 0; m < 4; ++m)
            acc[t][m] = (f32x4){0.f, 0.f, 0.f, 0.f};
    f32x4 acc32 = (f32x4){0.f, 0.f, 0.f, 0.f};

    auto loadB = [&](frag_t* dst, int kt) {
        #pragma unroll
        for (int t = 0; t < 4; ++t)
            dst[t] = *(const frag_t*)(wb + (size_t)((nt0 + t) * KT + kt) * 1024);
    };
    auto step = [&](const frag_t* b, int kt) {
        frag_t b32, a32;
        if (t32) {
            b32 = *(const frag_t*)(wb + (size_t)(32 * KT + kt) * 1024);
            a32 = *(const frag_t*)(a32base + kt * 64);
        }
        {   // chunk 0: m = 0..1 (live A = 8 regs)
            frag_t a[2];
            #pragma unroll
            for (int m = 0; m < 2; ++m)
                a[m] = *(const frag_t*)(abase + (size_t)(m * 16) * (RS * 2) + kt * 64);
            #pragma unroll
            for (int t = 0; t < 4; ++t)
                #pragma unroll
                for (int m = 0; m < 2; ++m)
                    acc[t][m] = __builtin_amdgcn_mfma_f32_16x16x32_bf16(b[t], a[m], acc[t][m], 0, 0, 0);
        }
        {   // chunk 1: m = 2..3
            frag_t a[2];
            #pragma unroll
            for (int m = 0; m < 2; ++m)
                a[m] = *(const frag_t*)(abase + (size_t)((m + 2) * 16) * (RS * 2) + kt * 64);
            #pragma unroll
            for (int t = 0; t < 4; ++t)
                #pragma unroll
                for (int m = 0; m < 2; ++m)
                    acc[t][m + 2] = __builtin_amdgcn_mfma_f32_16x16x32_bf16(b[t], a[m], acc[t][m + 2], 0, 0, 0);
        }
        if (t32)
            acc32 = __builtin_amdgcn_mfma_f32_16x16x32_bf16(b32, a32, acc32, 0, 0, 0);
    };

    frag_t bA[4], bB[4];
    loadB(bA, 0);
    #pragma unroll 1
    for (int kp = 0; kp < 8; ++kp) {
        loadB(bB, 2 * kp + 1);
        step(bA, 2 * kp);
        loadB(bA, 2 * kp + 2);
        step(bB, 2 * kp + 1);
    }
    step(bA, 16);

    __syncthreads();   // all A-reads done -> safe to overwrite h in place

    // epilogue: h = elu(z + b) + h, b64 granularity (4 consecutive cols per thread)
    #pragma unroll
    for (int t = 0; t < 4; ++t) {
        const int colb = (nt0 + t) * 16 + grp * 4;          // <= 496+12 < 520
        const float4 bb = *(const float4*)(bias + colb);
        #pragma unroll
        for (int m = 0; m < 4; ++m) {
            const int row = m * 16 + idx;
            char* p = h + (size_t)row * (RS * 2) + (size_t)colb * 2;
            ushort4 hv = *(const ushort4*)p;
            ushort4 o;
            o.x = f2bf(elu(acc[t][m][0] + bb.x) + bf2f(hv.x));
            o.y = f2bf(elu(acc[t][m][1] + bb.y) + bf2f(hv.y));
            o.z = f2bf(elu(acc[t][m][2] + bb.z) + bf2f(hv.z));
            o.w = f2bf(elu(acc[t][m][3] + bb.w) + bf2f(hv.w));
            *(ushort4*)p = o;
        }
    }
    if (t32) {   // cols 512..527, rows 16*wave..+15 (bias 0 past col 519)
        const int colb = 512 + grp * 4;
        float bb[4];
        #pragma unroll
        for (int q = 0; q < 4; ++q) bb[q] = (colb + q < F_DIM) ? bias[colb + q] : 0.0f;
        const int row = wave * 16 + idx;
        char* p = h + (size_t)row * (RS * 2) + (size_t)colb * 2;
        ushort4 hv = *(const ushort4*)p;
        ushort4 o;
        o.x = f2bf(elu(acc32[0] + bb[0]) + bf2f(hv.x));
        o.y = f2bf(elu(acc32[1] + bb[1]) + bf2f(hv.y));
        o.z = f2bf(elu(acc32[2] + bb[2]) + bf2f(hv.z));
        o.w = f2bf(elu(acc32[3] + bb[3]) + bf2f(hv.w));
        *(ushort4*)p = o;
    }
    __syncthreads();
}

__global__ __launch_bounds__(512, 4)
void edge_mlp_kernel(const float* __restrict__ X, const int* __restrict__ eidx,
                     const float* __restrict__ emb, const float* __restrict__ sef,
                     const float* __restrict__ b1, const float* __restrict__ b2,
                     const float* __restrict__ bout,
                     const unsigned short* __restrict__ W1p,
                     const unsigned short* __restrict__ W2p,
                     const unsigned short* __restrict__ Woutp,
                     float* __restrict__ out) {
    extern __shared__ char h[];          // 64 x 552 bf16, in-place panel
    const int tid  = threadIdx.x;
    const int wave = tid >> 6;           // 0..7
    const int lane = tid & 63;
    const long long base = (long long)blockIdx.x * BM;

    // ---- gather + f32->bf16 into h, wave w owns rows 8w..8w+7 ----
    // Lanes 0..15 fetch the wave's 16 indices (8 src + 8 dst); __shfl distributes.
    // Out-of-range edges CLAMPED (junk rows never stored -> harmless).
    // Outer loops rolled: 4 rows in flight caps VGPR pressure (R4-R6 spill lesson).
    int myidx = 0;
    if (lane < 16) {
        long long e = base + wave * 8 + (lane & 7);
        if (e >= E_EDGES) e = E_EDGES - 1;
        myidx = eidx[(long long)(lane >> 3) * E_EDGES + e];
    }

    #pragma unroll 1
    for (int g = 0; g < 2; ++g) {
        #pragma unroll
        for (int rr = 0; rr < 4; ++rr) {
            const int r = wave * 8 + g * 4 + rr;
            char* row = h + (size_t)r * (RS * 2);
            const int src = __shfl(myidx, g * 4 + rr);
            const int dst = __shfl(myidx, 8 + g * 4 + rr);
            float2 v = *(const float2*)(X + (long long)src * D_NODE + lane * 2);
            *(unsigned int*)(row + lane * 4) =
                (unsigned int)f2bf(v.x) | ((unsigned int)f2bf(v.y) << 16);
            float2 w = *(const float2*)(X + (long long)dst * D_NODE + lane * 2);
            *(unsigned int*)(row + 256 + lane * 4) =
                (unsigned int)f2bf(w.x) | ((unsigned int)f2bf(w.y) << 16);
        }
    }
    #pragma unroll 1
    for (int g = 0; g < 2; ++g) {
        #pragma unroll
        for (int rr = 0; rr < 4; ++rr) {
            if (lane < 50) {   // 200 emb floats per row
                long long e = base + wave * 8 + g * 4 + rr;
                if (e >= E_EDGES) e = E_EDGES - 1;
                char* row = h + (size_t)(wave * 8 + g * 4 + rr) * (RS * 2);
                float4 v = *(const float4*)(emb + e * D_EMB + (long long)lane * 4);
                unsigned int u0 = (unsigned int)f2bf(v.x) | ((unsigned int)f2bf(v.y) << 16);
                unsigned int u1 = (unsigned int)f2bf(v.z) | ((unsigned int)f2bf(v.w) << 16);
                *(uint2*)(row + 512 + lane * 8) = make_uint2(u0, u1);
            }
        }
    }
    #pragma unroll 1
    for (int q = 0; q < 2; ++q) {      // static: 4 rows per iteration (64 floats/row)
        const int r = wave * 8 + q * 4 + (lane >> 4);
        long long e = base + r;
        if (e >= E_EDGES) e = E_EDGES - 1;
        char* row = h + (size_t)r * (RS * 2);
        float4 v = *(const float4*)(sef + e * D_STATIC + (long long)(lane & 15) * 4);
        unsigned int u0 = (unsigned int)f2bf(v.x) | ((unsigned int)f2bf(v.y) << 16);
        unsigned int u1 = (unsigned int)f2bf(v.z) | ((unsigned int)f2bf(v.w) << 16);
        *(uint2*)(row + 912 + (lane & 15) * 8) = make_uint2(u0, u1);
        if ((lane & 15) < 6)          // zero pad cols 520..543 (48 B per row)
            *(uint2*)(row + 1040 + (lane & 15) * 8) = make_uint2(0u, 0u);
    }
    __syncthreads();

    layer_pass(h, W1p, b1, wave, lane);   // h = elu(h@W1+b1)+h
    layer_pass(h, W2p, b2, wave, lane);   // h = elu(h@W2+b2)+h

    // ---- output projection: waves 0..3, wave w owns rows 16w..16w+15 ----
    if (wave < 4) {
        const int idx = lane & 15;
        const int grp = lane >> 4;
        f32x4 acc = (f32x4){0.f, 0.f, 0.f, 0.f};
        #pragma unroll 1
        for (int kt = 0; kt < KT; ++kt) {
            frag_t b = *(const frag_t*)((const char*)Woutp + (size_t)kt * 1024 + (size_t)lane * 16);
            frag_t a = *(const frag_t*)(h + (size_t)(wave * 16 + idx) * (RS * 2) + kt * 64 + grp * 16);
            acc = __builtin_amdgcn_mfma_f32_16x16x32_bf16(b, a, acc, 0, 0, 0);
        }
        if (grp < 2) {   // cols 0..7 real, grp>=2 are n-pad
            const long long e = base + wave * 16 + idx;
            if (e < E_EDGES) {
                float4 bb = *(const float4*)(bout + grp * 4);
                float4 o = make_float4(acc[0] + bb.x, acc[1] + bb.y,
                                       acc[2] + bb.z, acc[3] + bb.w);
                *(float4*)(out + e * 8 + grp * 4) = o;
            }
        }
    }
}

extern "C" void kernel_launch(void* const* d_in, const int* in_sizes, int n_in,
                              void* d_out, int out_size, void* d_ws, size_t ws_size,
                              hipStream_t stream) {
    const float* X    = (const float*)d_in[0];
    const int*   eidx = (const int*)d_in[1];
    const float* emb  = (const float*)d_in[2];
    const float* sef  = (const float*)d_in[3];
    const float* W1   = (const float*)d_in[4];
    const float* b1   = (const float*)d_in[5];
    const float* W2   = (const float*)d_in[6];
    const float* b2   = (const float*)d_in[7];
    const float* Wout = (const float*)d_in[8];
    const float* bout = (const float*)d_in[9];
    float* out = (float*)d_out;

    unsigned short* W1p   = (unsigned short*)d_ws;                 // 33*17*512 bf16
    unsigned short* W2p   = W1p + (size_t)NT * KT * 512;
    unsigned short* Woutp = W2p + (size_t)NT * KT * 512;           // 17*512 bf16

    int total = NT * KT * 64;
    pack_w_kernel<<<(total + 255) / 256, 256, 0, stream>>>(W1, W1p, NT, F_DIM, F_DIM, F_DIM);
    pack_w_kernel<<<(total + 255) / 256, 256, 0, stream>>>(W2, W2p, NT, F_DIM, F_DIM, F_DIM);
    pack_w_kernel<<<(KT * 64 + 255) / 256, 256, 0, stream>>>(Wout, Woutp, 1, F_DIM, 8, 8);

    (void)hipFuncSetAttribute((const void*)edge_mlp_kernel,
                              hipFuncAttributeMaxDynamicSharedMemorySize, SMEM_BYTES);
    int nblocks = (E_EDGES + BM - 1) / BM;
    edge_mlp_kernel<<<nblocks, 512, SMEM_BYTES, stream>>>(
        X, eidx, emb, sef, b1, b2, bout, W1p, W2p, Woutp, out);
}

// Round 15
// 350.899 us; speedup vs baseline: 1.6458x; 1.6458x over previous
//
#include <hip/hip_runtime.h>
#include <hip/hip_bf16.h>

#define E_EDGES   250000
#define D_NODE    128
#define D_EMB     200
#define D_STATIC  64
#define F_DIM     520
#define NT        33        // n-tiles of 16 (528 real cols; tile 32 = cols 512..527)
#define KT        17        // k-steps of 32 (544 k padded; cols 528..543 zero)
#define RS        552       // LDS row stride bf16. MUST stay 16B-aligned (R9/R10:
                            // RS=564 = 8 mod 16 made odd-row ds_read_b128 misaligned
                            // -> 2x LDS time, -90%). 552 = 1104B, 276 dw mod 32 = 20,
                            // gcd 4 -> uniform 2 lanes/bank = free (m136). Optimal.
#define BM        64        // edges (rows) per block
#define SMEM_BYTES (BM * RS * 2)   // 70656 B -> 2 independent blocks/CU
                            // (R11/R13: 1 big block = barrier lockstep stall;
                            //  R14: ping-pong doesn't fit the 128-reg/wave budget
                            //  at 2 blocks/CU -> single-buffered B is the optimum)

typedef __attribute__((ext_vector_type(8))) short frag_t;   // 8 bf16 = 4 VGPR
typedef __attribute__((ext_vector_type(4))) float f32x4;

// Packed f32->bf16 pair conversion: ONE v_cvt_pk_bf16_f32 (RTNE) replaces ~8-10
// VALU ops of the scalar twiddle. R12 measured VALUBusy 43% > MfmaUtil 33% with
// ~105k twiddle-converted values per block-pair -> conversions were the largest
// VALU sink. (R10 factorial exonerated intrinsic-style converts; RS was the
// real R9 culprit.)
__device__ __forceinline__ unsigned int cvtpk(float lo, float hi) {
    unsigned int r;
    asm("v_cvt_pk_bf16_f32 %0, %1, %2" : "=v"(r) : "v"(lo), "v"(hi));
    return r;
}

// Scalar RNE twiddle: cold paths only (pack kernels).
__device__ __forceinline__ unsigned short f2bf(float x) {
    union { float f; unsigned int u; } v; v.f = x;
    unsigned int r = v.u + 0x7FFFu + ((v.u >> 16) & 1u);   // RTNE
    return (unsigned short)(r >> 16);
}
__device__ __forceinline__ float bf2f(unsigned short u) {
    union { float f; unsigned int i; } v; v.i = ((unsigned int)u) << 16; return v.f;
}
__device__ __forceinline__ float elu(float z) {
    return (z > 0.0f) ? z : (__expf(z) - 1.0f);
}

// Pack W[k][n] (f32, row-major, ldw) into fragment-ordered bf16:
// Wp[((nt*KT + kt)*64 + lane)*8 + j] = W[kt*32 + (lane>>4)*8 + j][nt*16 + (lane&15)]
// zero outside (krows, ncols).
__global__ void pack_w_kernel(const float* __restrict__ W, unsigned short* __restrict__ Wp,
                              int ntiles, int krows, int ncols, int ldw) {
    int t = blockIdx.x * blockDim.x + threadIdx.x;
    if (t >= ntiles * KT * 64) return;
    int nt   = t / (KT * 64);
    int rem  = t % (KT * 64);
    int kt   = rem / 64;
    int lane = rem % 64;
    int n  = nt * 16 + (lane & 15);
    int kb = kt * 32 + (lane >> 4) * 8;
    unsigned short v[8];
    #pragma unroll
    for (int j = 0; j < 8; ++j) {
        int k = kb + j;
        float w = (k < krows && n < ncols) ? W[(long long)k * ldw + n] : 0.0f;
        v[j] = f2bf(w);
    }
    unsigned short* dst = Wp + (long long)t * 8;
    #pragma unroll
    for (int j = 0; j < 8; ++j) dst[j] = v[j];
}

// One residual-MLP layer, in place on the 64x552 bf16 LDS panel.
// 8 waves: wave w owns ntiles 4w..4w+3 over all 64 rows (acc[4][4]=64 regs);
// waves 0..3 also fold tile 32 (cols 512..527), rows 16w..16w+15.
// Single-buffered B (R14: ping-pong spills at the 2-block/CU register budget),
// A chunked 2-at-a-time, K-loop ROLLED (R4-R6: unrolled bodies spill ~500MB).
__device__ __forceinline__ void layer_pass(char* __restrict__ h,
                                           const unsigned short* __restrict__ Wp,
                                           const float* __restrict__ bias,
                                           int wave, int lane) {
    const int idx = lane & 15;
    const int grp = lane >> 4;
    const int nt0 = wave * 4;
    const bool t32 = (wave < 4);
    const char* wb = (const char*)Wp + (size_t)lane * 16;
    const char* abase   = h + (size_t)idx * (RS * 2) + grp * 16;
    const char* a32base = h + (size_t)(wave * 16 + idx) * (RS * 2) + grp * 16;

    f32x4 acc[4][4];
    #pragma unroll
    for (int t = 0; t < 4; ++t)
        #pragma unroll
        for (int m = 0; m < 4; ++m)
            acc[t][m] = (f32x4){0.f, 0.f, 0.f, 0.f};
    f32x4 acc32 = (f32x4){0.f, 0.f, 0.f, 0.f};

    #pragma unroll 1
    for (int kt = 0; kt < KT; ++kt) {
        frag_t b[4];
        #pragma unroll
        for (int t = 0; t < 4; ++t)
            b[t] = *(const frag_t*)(wb + (size_t)((nt0 + t) * KT + kt) * 1024);
        frag_t b32, a32;
        if (t32) {
            b32 = *(const frag_t*)(wb + (size_t)(32 * KT + kt) * 1024);
            a32 = *(const frag_t*)(a32base + kt * 64);
        }
        {   // chunk 0: m = 0..1 (live A = 8 regs)
            frag_t a[2];
            #pragma unroll
            for (int m = 0; m < 2; ++m)
                a[m] = *(const frag_t*)(abase + (size_t)(m * 16) * (RS * 2) + kt * 64);
            #pragma unroll
            for (int t = 0; t < 4; ++t)
                #pragma unroll
                for (int m = 0; m < 2; ++m)
                    acc[t][m] = __builtin_amdgcn_mfma_f32_16x16x32_bf16(b[t], a[m], acc[t][m], 0, 0, 0);
        }
        {   // chunk 1: m = 2..3
            frag_t a[2];
            #pragma unroll
            for (int m = 0; m < 2; ++m)
                a[m] = *(const frag_t*)(abase + (size_t)((m + 2) * 16) * (RS * 2) + kt * 64);
            #pragma unroll
            for (int t = 0; t < 4; ++t)
                #pragma unroll
                for (int m = 0; m < 2; ++m)
                    acc[t][m + 2] = __builtin_amdgcn_mfma_f32_16x16x32_bf16(b[t], a[m], acc[t][m + 2], 0, 0, 0);
        }
        if (t32)
            acc32 = __builtin_amdgcn_mfma_f32_16x16x32_bf16(b32, a32, acc32, 0, 0, 0);
    }

    __syncthreads();   // all A-reads done -> safe to overwrite h in place

    // epilogue: h = elu(z + b) + h; conversions via packed cvt (2 insts per 4 vals)
    #pragma unroll
    for (int t = 0; t < 4; ++t) {
        const int colb = (nt0 + t) * 16 + grp * 4;          // <= 496+12 < 520
        const float4 bb = *(const float4*)(bias + colb);
        #pragma unroll
        for (int m = 0; m < 4; ++m) {
            const int row = m * 16 + idx;
            char* p = h + (size_t)row * (RS * 2) + (size_t)colb * 2;
            ushort4 hv = *(const ushort4*)p;
            float z0 = elu(acc[t][m][0] + bb.x) + bf2f(hv.x);
            float z1 = elu(acc[t][m][1] + bb.y) + bf2f(hv.y);
            float z2 = elu(acc[t][m][2] + bb.z) + bf2f(hv.z);
            float z3 = elu(acc[t][m][3] + bb.w) + bf2f(hv.w);
            *(uint2*)p = make_uint2(cvtpk(z0, z1), cvtpk(z2, z3));
        }
    }
    if (t32) {   // cols 512..527, rows 16*wave..+15 (bias 0 past col 519)
        const int colb = 512 + grp * 4;
        float bb[4];
        #pragma unroll
        for (int q = 0; q < 4; ++q) bb[q] = (colb + q < F_DIM) ? bias[colb + q] : 0.0f;
        const int row = wave * 16 + idx;
        char* p = h + (size_t)row * (RS * 2) + (size_t)colb * 2;
        ushort4 hv = *(const ushort4*)p;
        float z0 = elu(acc32[0] + bb[0]) + bf2f(hv.x);
        float z1 = elu(acc32[1] + bb[1]) + bf2f(hv.y);
        float z2 = elu(acc32[2] + bb[2]) + bf2f(hv.z);
        float z3 = elu(acc32[3] + bb[3]) + bf2f(hv.w);
        *(uint2*)p = make_uint2(cvtpk(z0, z1), cvtpk(z2, z3));
    }
    __syncthreads();
}

__global__ __launch_bounds__(512, 4)
void edge_mlp_kernel(const float* __restrict__ X, const int* __restrict__ eidx,
                     const float* __restrict__ emb, const float* __restrict__ sef,
                     const float* __restrict__ b1, const float* __restrict__ b2,
                     const float* __restrict__ bout,
                     const unsigned short* __restrict__ W1p,
                     const unsigned short* __restrict__ W2p,
                     const unsigned short* __restrict__ Woutp,
                     float* __restrict__ out) {
    extern __shared__ char h[];          // 64 x 552 bf16, in-place panel
    const int tid  = threadIdx.x;
    const int wave = tid >> 6;           // 0..7
    const int lane = tid & 63;
    const long long base = (long long)blockIdx.x * BM;

    // ---- gather + f32->bf16 into h, wave w owns rows 8w..8w+7 ----
    // Lanes 0..15 fetch the wave's 16 indices (8 src + 8 dst); __shfl distributes.
    // Out-of-range edges CLAMPED (junk rows never stored -> harmless).
    // Outer loops rolled: 4 rows in flight caps VGPR pressure (R4-R6 spill lesson).
    int myidx = 0;
    if (lane < 16) {
        long long e = base + wave * 8 + (lane & 7);
        if (e >= E_EDGES) e = E_EDGES - 1;
        myidx = eidx[(long long)(lane >> 3) * E_EDGES + e];
    }

    #pragma unroll 1
    for (int g = 0; g < 2; ++g) {
        #pragma unroll
        for (int rr = 0; rr < 4; ++rr) {
            const int r = wave * 8 + g * 4 + rr;
            char* row = h + (size_t)r * (RS * 2);
            const int src = __shfl(myidx, g * 4 + rr);
            const int dst = __shfl(myidx, 8 + g * 4 + rr);
            float2 v = *(const float2*)(X + (long long)src * D_NODE + lane * 2);
            *(unsigned int*)(row + lane * 4) = cvtpk(v.x, v.y);
            float2 w = *(const float2*)(X + (long long)dst * D_NODE + lane * 2);
            *(unsigned int*)(row + 256 + lane * 4) = cvtpk(w.x, w.y);
        }
    }
    #pragma unroll 1
    for (int g = 0; g < 2; ++g) {
        #pragma unroll
        for (int rr = 0; rr < 4; ++rr) {
            if (lane < 50) {   // 200 emb floats per row
                long long e = base + wave * 8 + g * 4 + rr;
                if (e >= E_EDGES) e = E_EDGES - 1;
                char* row = h + (size_t)(wave * 8 + g * 4 + rr) * (RS * 2);
                float4 v = *(const float4*)(emb + e * D_EMB + (long long)lane * 4);
                *(uint2*)(row + 512 + lane * 8) =
                    make_uint2(cvtpk(v.x, v.y), cvtpk(v.z, v.w));
            }
        }
    }
    #pragma unroll 1
    for (int q = 0; q < 2; ++q) {      // static: 4 rows per iteration (64 floats/row)
        const int r = wave * 8 + q * 4 + (lane >> 4);
        long long e = base + r;
        if (e >= E_EDGES) e = E_EDGES - 1;
        char* row = h + (size_t)r * (RS * 2);
        float4 v = *(const float4*)(sef + e * D_STATIC + (long long)(lane & 15) * 4);
        *(uint2*)(row + 912 + (lane & 15) * 8) =
            make_uint2(cvtpk(v.x, v.y), cvtpk(v.z, v.w));
        if ((lane & 15) < 6)          // zero pad cols 520..543 (48 B per row)
            *(uint2*)(row + 1040 + (lane & 15) * 8) = make_uint2(0u, 0u);
    }
    __syncthreads();

    layer_pass(h, W1p, b1, wave, lane);   // h = elu(h@W1+b1)+h
    layer_pass(h, W2p, b2, wave, lane);   // h = elu(h@W2+b2)+h

    // ---- output projection: waves 0..3, wave w owns rows 16w..16w+15 ----
    if (wave < 4) {
        const int idx = lane & 15;
        const int grp = lane >> 4;
        f32x4 acc = (f32x4){0.f, 0.f, 0.f, 0.f};
        #pragma unroll 1
        for (int kt = 0; kt < KT; ++kt) {
            frag_t b = *(const frag_t*)((const char*)Woutp + (size_t)kt * 1024 + (size_t)lane * 16);
            frag_t a = *(const frag_t*)(h + (size_t)(wave * 16 + idx) * (RS * 2) + kt * 64 + grp * 16);
            acc = __builtin_amdgcn_mfma_f32_16x16x32_bf16(b, a, acc, 0, 0, 0);
        }
        if (grp < 2) {   // cols 0..7 real, grp>=2 are n-pad
            const long long e = base + wave * 16 + idx;
            if (e < E_EDGES) {
                float4 bb = *(const float4*)(bout + grp * 4);
                float4 o = make_float4(acc[0] + bb.x, acc[1] + bb.y,
                                       acc[2] + bb.z, acc[3] + bb.w);
                *(float4*)(out + e * 8 + grp * 4) = o;
            }
        }
    }
}

extern "C" void kernel_launch(void* const* d_in, const int* in_sizes, int n_in,
                              void* d_out, int out_size, void* d_ws, size_t ws_size,
                              hipStream_t stream) {
    const float* X    = (const float*)d_in[0];
    const int*   eidx = (const int*)d_in[1];
    const float* emb  = (const float*)d_in[2];
    const float* sef  = (const float*)d_in[3];
    const float* W1   = (const float*)d_in[4];
    const float* b1   = (const float*)d_in[5];
    const float* W2   = (const float*)d_in[6];
    const float* b2   = (const float*)d_in[7];
    const float* Wout = (const float*)d_in[8];
    const float* bout = (const float*)d_in[9];
    float* out = (float*)d_out;

    unsigned short* W1p   = (unsigned short*)d_ws;                 // 33*17*512 bf16
    unsigned short* W2p   = W1p + (size_t)NT * KT * 512;
    unsigned short* Woutp = W2p + (size_t)NT * KT * 512;           // 17*512 bf16

    int total = NT * KT * 64;
    pack_w_kernel<<<(total + 255) / 256, 256, 0, stream>>>(W1, W1p, NT, F_DIM, F_DIM, F_DIM);
    pack_w_kernel<<<(total + 255) / 256, 256, 0, stream>>>(W2, W2p, NT, F_DIM, F_DIM, F_DIM);
    pack_w_kernel<<<(KT * 64 + 255) / 256, 256, 0, stream>>>(Wout, Woutp, 1, F_DIM, 8, 8);

    (void)hipFuncSetAttribute((const void*)edge_mlp_kernel,
                              hipFuncAttributeMaxDynamicSharedMemorySize, SMEM_BYTES);
    int nblocks = (E_EDGES + BM - 1) / BM;
    edge_mlp_kernel<<<nblocks, 512, SMEM_BYTES, stream>>>(
        X, eidx, emb, sef, b1, b2, bout, W1p, W2p, Woutp, out);
}